// Round 2
// baseline (706.299 us; speedup 1.0000x reference)
//
#include <hip/hip_runtime.h>

#define NN 3000
#define NBATCH 8
#define TP 12
#define CAP (1 << 19)

// ---------------- Laplacian build ----------------

__global__ void deg_kernel(const float* __restrict__ A, float* __restrict__ dinv,
                           int* __restrict__ rowcnt) {
    int n = blockIdx.x;
    const float* row = A + (size_t)n * NN;
    float s = 0.f; int c = 0;
    for (int m = threadIdx.x; m < NN; m += blockDim.x) {
        if (m == n) continue;
        float a = row[m];
        if (a != 0.f) { s += a; c += 1; }
    }
    __shared__ float ssum[256];
    __shared__ int   scnt[256];
    ssum[threadIdx.x] = s; scnt[threadIdx.x] = c;
    __syncthreads();
    for (int st = 128; st > 0; st >>= 1) {
        if ((int)threadIdx.x < st) {
            ssum[threadIdx.x] += ssum[threadIdx.x + st];
            scnt[threadIdx.x] += scnt[threadIdx.x + st];
        }
        __syncthreads();
    }
    if (threadIdx.x == 0) {
        float d = ssum[0];
        dinv[n] = d > 0.f ? 1.0f / sqrtf(d) : 0.f;
        rowcnt[n] = scnt[0];
    }
}

// single-block exclusive scan over rowcnt -> row_ptr[0..NN]
__global__ void scan_kernel(const int* __restrict__ rowcnt, int* __restrict__ row_ptr) {
    __shared__ int part[1024];
    int t = threadIdx.x;
    int base = t * 3;
    int a0 = (base + 0 < NN) ? rowcnt[base + 0] : 0;
    int a1 = (base + 1 < NN) ? rowcnt[base + 1] : 0;
    int a2 = (base + 2 < NN) ? rowcnt[base + 2] : 0;
    part[t] = a0 + a1 + a2;
    __syncthreads();
    for (int off = 1; off < 1024; off <<= 1) {
        int add = (t >= off) ? part[t - off] : 0;
        __syncthreads();
        part[t] += add;
        __syncthreads();
    }
    int excl = (t > 0) ? part[t - 1] : 0;
    int i0 = base, i1 = base + 1, i2 = base + 2;
    if (i0 <= NN) row_ptr[i0] = excl;
    if (i1 <= NN) row_ptr[i1] = excl + a0;
    if (i2 <= NN) row_ptr[i2] = excl + a0 + a1;
}

// one wave per row; deterministic in-order compaction
__global__ void fill_kernel(const float* __restrict__ A, const float* __restrict__ dinv,
                            const int* __restrict__ row_ptr, int* __restrict__ col_idx,
                            float* __restrict__ val) {
    int n = blockIdx.x;
    int lane = threadIdx.x;
    const float* row = A + (size_t)n * NN;
    int base = row_ptr[n];
    float dn = dinv[n];
    for (int start = 0; start < NN; start += 64) {
        int m = start + lane;
        float a = 0.f; bool nz = false;
        if (m < NN && m != n) {
            a = row[m];
            nz = (a != 0.f);
        }
        unsigned long long mask = __ballot(nz);
        int off = __popcll(mask & ((1ull << lane) - 1ull));
        if (nz) {
            int idx = base + off;
            if (idx < CAP) { col_idx[idx] = m; val[idx] = -dn * a * dinv[m]; }
        }
        base += __popcll(mask);
    }
}

// ---------------- SpMM: y = L x  (SECOND: y = 2*L*x - x0) ----------------

template <bool SECOND>
__global__ void spmm_kernel(const int* __restrict__ row_ptr, const int* __restrict__ col_idx,
                            const float* __restrict__ val, const float* __restrict__ x,
                            const float* __restrict__ x0, float* __restrict__ y, int F) {
    int n = blockIdx.x;
    int f = blockIdx.y * blockDim.x + threadIdx.x;
    if (f >= F) return;
    int s = row_ptr[n], e = row_ptr[n + 1];
    float acc = 0.f;
    for (int i = s; i < e; ++i) {
        int m = col_idx[i];
        float w = val[i];
        acc += w * x[(size_t)m * F + f];
    }
    if (SECOND) acc = 2.f * acc - x0[(size_t)n * F + f];
    y[(size_t)n * F + f] = acc;
}

// ---------------- cheb-combine + bias + relu + tconv(3,pad1) + relu ----------------

template <int CIN, int COUT>
__global__ void combine_kernel(const float* __restrict__ x0, const float* __restrict__ t1,
                               const float* __restrict__ t2, const float* __restrict__ W,
                               const float* __restrict__ bg, const float* __restrict__ cw,
                               const float* __restrict__ cb, float* __restrict__ out) {
    int nb = blockIdx.x;  // n*NBATCH + b
    int co = threadIdx.x;
    __shared__ float sx[3][CIN];
    __shared__ float sz[COUT];
    const float* r0 = x0 + (size_t)nb * CIN;
    const float* r1 = t1 + (size_t)nb * CIN;
    const float* r2 = t2 + (size_t)nb * CIN;
    for (int i = threadIdx.x; i < 3 * CIN; i += blockDim.x) {
        int k = i / CIN, ci = i % CIN;
        const float* r = (k == 0) ? r0 : (k == 1) ? r1 : r2;
        sx[k][ci] = r[ci];
    }
    __syncthreads();
    float s = bg[co];
    for (int k = 0; k < 3; ++k) {
        const float* Wk = W + (size_t)k * CIN * COUT;
        for (int ci = 0; ci < CIN; ++ci) {
            s += sx[k][ci] * Wk[ci * COUT + co];
        }
    }
    sz[co] = fmaxf(s, 0.f);
    __syncthreads();
    float w0 = cw[0], w1 = cw[1], w2 = cw[2], bb = cb[0];
    float left  = (co > 0) ? sz[co - 1] : 0.f;
    float right = (co < COUT - 1) ? sz[co + 1] : 0.f;
    float o = w0 * left + w1 * sz[co] + w2 * right + bb;
    out[(size_t)nb * COUT + co] = fmaxf(o, 0.f);
}

// ---------------- final linear (32->12) + relu + fusion accumulate ----------------

__global__ void finald_kernel(const float* __restrict__ z2, const float* __restrict__ WD,
                              const float* __restrict__ bD, const float* __restrict__ Fb,
                              float* __restrict__ yacc, int add) {
    int idx = blockIdx.x * blockDim.x + threadIdx.x;
    if (idx >= NN * NBATCH * TP) return;
    int tp = idx % TP;
    int nb = idx / TP;
    float s = bD[tp];
    const float* z = z2 + (size_t)nb * 32;
    for (int c = 0; c < 32; ++c) s += z[c] * WD[c * TP + tp];
    s = fmaxf(s, 0.f) * Fb[tp];
    if (add) s += yacc[idx];
    yacc[idx] = s;
}

__global__ void out_kernel(const float* __restrict__ yacc, float* __restrict__ out) {
    int idx = blockIdx.x * blockDim.x + threadIdx.x;
    if (idx >= NN * NBATCH * TP) return;
    int tp = idx % TP;
    int nb = idx / TP;
    int b = nb % NBATCH;
    int n = nb / NBATCH;
    out[((size_t)b * NN + n) * TP + tp] = yacc[idx];
}

// transpose X (B,N,1,T) f32 -> xt (N,B,T) f32
__global__ void tr_kernel(const float* __restrict__ X, float* __restrict__ xt, int T) {
    int idx = blockIdx.x * blockDim.x + threadIdx.x;
    if (idx >= NN * NBATCH * T) return;
    int t = idx % T;
    int nb = idx / T;
    int b = nb % NBATCH;
    int n = nb / NBATCH;
    xt[idx] = X[((size_t)b * NN + n) * T + t];
}

// ---------------- launcher ----------------

static inline size_t align256(size_t x) { return (x + 255) & ~(size_t)255; }

extern "C" void kernel_launch(void* const* d_in, const int* in_sizes, int n_in,
                              void* d_out, int out_size, void* d_ws, size_t ws_size,
                              hipStream_t stream) {
    const float* Xh = (const float*)d_in[0];
    const float* Xd = (const float*)d_in[1];
    const float* Xw = (const float*)d_in[2];
    const float* A  = (const float*)d_in[3];
    const float* WD = (const float*)d_in[28];
    const float* bD = (const float*)d_in[29];

    // workspace carve
    char* p = (char*)d_ws;
    float* dinv   = (float*)p; p += align256(NN * 4);
    int* row_ptr  = (int*)p;   p += align256((NN + 1) * 4);
    int* rowcnt   = (int*)p;   p += align256(NN * 4);
    int* col_idx  = (int*)p;   p += align256((size_t)CAP * 4);
    float* val    = (float*)p; p += align256((size_t)CAP * 4);
    float* b_in   = (float*)p; p += align256((size_t)NN * NBATCH * 64 * 4);
    float* b_t1   = (float*)p; p += align256((size_t)NN * NBATCH * 64 * 4);
    float* b_t2   = (float*)p; p += align256((size_t)NN * NBATCH * 64 * 4);
    float* b_z1   = (float*)p; p += align256((size_t)NN * NBATCH * 64 * 4);
    float* b_z2   = (float*)p; p += align256((size_t)NN * NBATCH * 32 * 4);
    float* yacc   = (float*)p; p += align256((size_t)NN * NBATCH * TP * 4);

    deg_kernel<<<NN, 256, 0, stream>>>(A, dinv, rowcnt);
    scan_kernel<<<1, 1024, 0, stream>>>(rowcnt, row_ptr);
    fill_kernel<<<NN, 64, 0, stream>>>(A, dinv, row_ptr, col_idx, val);

    struct BranchP {
        const float *X; int T;
        const float *W1, *b1, *c1w, *c1b, *W2, *b2, *c2w, *c2b, *F;
    };
    BranchP br[3] = {
        { Xh, 24, (const float*)d_in[4],  (const float*)d_in[5],  (const float*)d_in[6],
                  (const float*)d_in[7],  (const float*)d_in[8],  (const float*)d_in[9],
                  (const float*)d_in[10], (const float*)d_in[11], (const float*)d_in[30] },
        { Xd, 12, (const float*)d_in[12], (const float*)d_in[13], (const float*)d_in[14],
                  (const float*)d_in[15], (const float*)d_in[16], (const float*)d_in[17],
                  (const float*)d_in[18], (const float*)d_in[19], (const float*)d_in[31] },
        { Xw, 24, (const float*)d_in[20], (const float*)d_in[21], (const float*)d_in[22],
                  (const float*)d_in[23], (const float*)d_in[24], (const float*)d_in[25],
                  (const float*)d_in[26], (const float*)d_in[27], (const float*)d_in[32] }
    };

    for (int i = 0; i < 3; ++i) {
        const BranchP& bp = br[i];
        int T = bp.T;
        int nelem = NN * NBATCH * T;
        tr_kernel<<<(nelem + 255) / 256, 256, 0, stream>>>(bp.X, b_in, T);

        // Block 1: Cin=T -> 64
        int F1 = NBATCH * T;
        int bd1 = (F1 <= 256) ? F1 : 256;
        dim3 g1(NN, (F1 + bd1 - 1) / bd1);
        spmm_kernel<false><<<g1, bd1, 0, stream>>>(row_ptr, col_idx, val, b_in, nullptr, b_t1, F1);
        spmm_kernel<true><<<g1, bd1, 0, stream>>>(row_ptr, col_idx, val, b_t1, b_in, b_t2, F1);
        if (T == 24) {
            combine_kernel<24, 64><<<NN * NBATCH, 64, 0, stream>>>(
                b_in, b_t1, b_t2, bp.W1, bp.b1, bp.c1w, bp.c1b, b_z1);
        } else {
            combine_kernel<12, 64><<<NN * NBATCH, 64, 0, stream>>>(
                b_in, b_t1, b_t2, bp.W1, bp.b1, bp.c1w, bp.c1b, b_z1);
        }

        // Block 2: 64 -> 32
        int F2 = NBATCH * 64;  // 512
        dim3 g2(NN, 2);
        spmm_kernel<false><<<g2, 256, 0, stream>>>(row_ptr, col_idx, val, b_z1, nullptr, b_t1, F2);
        spmm_kernel<true><<<g2, 256, 0, stream>>>(row_ptr, col_idx, val, b_t1, b_z1, b_t2, F2);
        combine_kernel<64, 32><<<NN * NBATCH, 32, 0, stream>>>(
            b_z1, b_t1, b_t2, bp.W2, bp.b2, bp.c2w, bp.c2b, b_z2);

        int ntot = NN * NBATCH * TP;
        finald_kernel<<<(ntot + 255) / 256, 256, 0, stream>>>(b_z2, WD, bD, bp.F, yacc, i > 0);
    }

    int ntot = NN * NBATCH * TP;
    out_kernel<<<(ntot + 255) / 256, 256, 0, stream>>>(yacc, (float*)d_out);
}

// Round 3
// 384.656 us; speedup vs baseline: 1.8362x; 1.8362x over previous
//
#include <hip/hip_runtime.h>

#define NN 3000
#define NBATCH 8
#define TP 12
#define CAP (1 << 19)

// ---------------- Laplacian build ----------------

__global__ void deg_kernel(const float* __restrict__ A, float* __restrict__ dinv,
                           int* __restrict__ rowcnt) {
    int n = blockIdx.x;
    const float* row = A + (size_t)n * NN;
    float s = 0.f; int c = 0;
    for (int m = threadIdx.x; m < NN; m += blockDim.x) {
        if (m == n) continue;
        float a = row[m];
        if (a != 0.f) { s += a; c += 1; }
    }
    __shared__ float ssum[256];
    __shared__ int   scnt[256];
    ssum[threadIdx.x] = s; scnt[threadIdx.x] = c;
    __syncthreads();
    for (int st = 128; st > 0; st >>= 1) {
        if ((int)threadIdx.x < st) {
            ssum[threadIdx.x] += ssum[threadIdx.x + st];
            scnt[threadIdx.x] += scnt[threadIdx.x + st];
        }
        __syncthreads();
    }
    if (threadIdx.x == 0) {
        float d = ssum[0];
        dinv[n] = d > 0.f ? 1.0f / sqrtf(d) : 0.f;
        rowcnt[n] = scnt[0];
    }
}

// single-block exclusive scan over rowcnt -> row_ptr[0..NN]
__global__ void scan_kernel(const int* __restrict__ rowcnt, int* __restrict__ row_ptr) {
    __shared__ int part[1024];
    int t = threadIdx.x;
    int base = t * 3;
    int a0 = (base + 0 < NN) ? rowcnt[base + 0] : 0;
    int a1 = (base + 1 < NN) ? rowcnt[base + 1] : 0;
    int a2 = (base + 2 < NN) ? rowcnt[base + 2] : 0;
    part[t] = a0 + a1 + a2;
    __syncthreads();
    for (int off = 1; off < 1024; off <<= 1) {
        int add = (t >= off) ? part[t - off] : 0;
        __syncthreads();
        part[t] += add;
        __syncthreads();
    }
    int excl = (t > 0) ? part[t - 1] : 0;
    int i0 = base, i1 = base + 1, i2 = base + 2;
    if (i0 <= NN) row_ptr[i0] = excl;
    if (i1 <= NN) row_ptr[i1] = excl + a0;
    if (i2 <= NN) row_ptr[i2] = excl + a0 + a1;
}

// one wave per row; deterministic in-order compaction
__global__ void fill_kernel(const float* __restrict__ A, const float* __restrict__ dinv,
                            const int* __restrict__ row_ptr, int* __restrict__ col_idx,
                            float* __restrict__ val) {
    int n = blockIdx.x;
    int lane = threadIdx.x;
    const float* row = A + (size_t)n * NN;
    int base = row_ptr[n];
    float dn = dinv[n];
    for (int start = 0; start < NN; start += 64) {
        int m = start + lane;
        float a = 0.f; bool nz = false;
        if (m < NN && m != n) {
            a = row[m];
            nz = (a != 0.f);
        }
        unsigned long long mask = __ballot(nz);
        int off = __popcll(mask & ((1ull << lane) - 1ull));
        if (nz) {
            int idx = base + off;
            if (idx < CAP) { col_idx[idx] = m; val[idx] = -dn * a * dinv[m]; }
        }
        base += __popcll(mask);
    }
}

// ---------------- SpMM: y = L x  (SECOND: y = 2*L*x - x0) ----------------
// Block-uniform (col,val) staged in LDS (pre-scaled col by F, padded to 8),
// 8-way unrolled gather loop with 4 independent accumulators for ILP.

#define SPMM_CHUNK 256

template <bool SECOND>
__global__ void spmm_kernel(const int* __restrict__ row_ptr, const int* __restrict__ col_idx,
                            const float* __restrict__ val, const float* __restrict__ x,
                            const float* __restrict__ x0, float* __restrict__ y, int F) {
    int n = blockIdx.x;
    int f = blockIdx.y * blockDim.x + threadIdx.x;
    __shared__ int   scol[SPMM_CHUNK];
    __shared__ float sval[SPMM_CHUNK];
    int s = row_ptr[n], e = row_ptr[n + 1];
    float acc0 = 0.f, acc1 = 0.f, acc2 = 0.f, acc3 = 0.f;
    for (int base = s; base < e; base += SPMM_CHUNK) {
        int cnt = e - base;
        if (cnt > SPMM_CHUNK) cnt = SPMM_CHUNK;
        int cnt8 = (cnt + 7) & ~7;
        for (int i = threadIdx.x; i < cnt8; i += blockDim.x) {
            if (i < cnt) {
                scol[i] = col_idx[base + i] * F;
                sval[i] = val[base + i];
            } else {
                scol[i] = 0;
                sval[i] = 0.f;
            }
        }
        __syncthreads();
        if (f < F) {
            for (int i = 0; i < cnt8; i += 8) {
                int   c0 = scol[i + 0], c1 = scol[i + 1], c2 = scol[i + 2], c3 = scol[i + 3];
                int   c4 = scol[i + 4], c5 = scol[i + 5], c6 = scol[i + 6], c7 = scol[i + 7];
                float w0 = sval[i + 0], w1 = sval[i + 1], w2 = sval[i + 2], w3 = sval[i + 3];
                float w4 = sval[i + 4], w5 = sval[i + 5], w6 = sval[i + 6], w7 = sval[i + 7];
                float g0 = x[c0 + f], g1 = x[c1 + f], g2 = x[c2 + f], g3 = x[c3 + f];
                float g4 = x[c4 + f], g5 = x[c5 + f], g6 = x[c6 + f], g7 = x[c7 + f];
                acc0 += w0 * g0; acc1 += w1 * g1; acc2 += w2 * g2; acc3 += w3 * g3;
                acc0 += w4 * g4; acc1 += w5 * g5; acc2 += w6 * g6; acc3 += w7 * g7;
            }
        }
        __syncthreads();
    }
    if (f >= F) return;
    float acc = (acc0 + acc1) + (acc2 + acc3);
    if (SECOND) acc = 2.f * acc - x0[(size_t)n * F + f];
    y[(size_t)n * F + f] = acc;
}

// ---------------- cheb-combine + bias + relu + tconv(3,pad1) + relu ----------------

template <int CIN, int COUT>
__global__ void combine_kernel(const float* __restrict__ x0, const float* __restrict__ t1,
                               const float* __restrict__ t2, const float* __restrict__ W,
                               const float* __restrict__ bg, const float* __restrict__ cw,
                               const float* __restrict__ cb, float* __restrict__ out) {
    int nb = blockIdx.x;  // n*NBATCH + b
    int co = threadIdx.x;
    __shared__ float sx[3][CIN];
    __shared__ float sz[COUT];
    const float* r0 = x0 + (size_t)nb * CIN;
    const float* r1 = t1 + (size_t)nb * CIN;
    const float* r2 = t2 + (size_t)nb * CIN;
    for (int i = threadIdx.x; i < 3 * CIN; i += blockDim.x) {
        int k = i / CIN, ci = i % CIN;
        const float* r = (k == 0) ? r0 : (k == 1) ? r1 : r2;
        sx[k][ci] = r[ci];
    }
    __syncthreads();
    float s = bg[co];
    for (int k = 0; k < 3; ++k) {
        const float* Wk = W + (size_t)k * CIN * COUT;
        for (int ci = 0; ci < CIN; ++ci) {
            s += sx[k][ci] * Wk[ci * COUT + co];
        }
    }
    sz[co] = fmaxf(s, 0.f);
    __syncthreads();
    float w0 = cw[0], w1 = cw[1], w2 = cw[2], bb = cb[0];
    float left  = (co > 0) ? sz[co - 1] : 0.f;
    float right = (co < COUT - 1) ? sz[co + 1] : 0.f;
    float o = w0 * left + w1 * sz[co] + w2 * right + bb;
    out[(size_t)nb * COUT + co] = fmaxf(o, 0.f);
}

// ---------------- final linear (32->12) + relu + fusion accumulate ----------------

__global__ void finald_kernel(const float* __restrict__ z2, const float* __restrict__ WD,
                              const float* __restrict__ bD, const float* __restrict__ Fb,
                              float* __restrict__ yacc, int add) {
    int idx = blockIdx.x * blockDim.x + threadIdx.x;
    if (idx >= NN * NBATCH * TP) return;
    int tp = idx % TP;
    int nb = idx / TP;
    float s = bD[tp];
    const float* z = z2 + (size_t)nb * 32;
    for (int c = 0; c < 32; ++c) s += z[c] * WD[c * TP + tp];
    s = fmaxf(s, 0.f) * Fb[tp];
    if (add) s += yacc[idx];
    yacc[idx] = s;
}

__global__ void out_kernel(const float* __restrict__ yacc, float* __restrict__ out) {
    int idx = blockIdx.x * blockDim.x + threadIdx.x;
    if (idx >= NN * NBATCH * TP) return;
    int tp = idx % TP;
    int nb = idx / TP;
    int b = nb % NBATCH;
    int n = nb / NBATCH;
    out[((size_t)b * NN + n) * TP + tp] = yacc[idx];
}

// transpose X (B,N,1,T) f32 -> xt (N,B,T) f32
__global__ void tr_kernel(const float* __restrict__ X, float* __restrict__ xt, int T) {
    int idx = blockIdx.x * blockDim.x + threadIdx.x;
    if (idx >= NN * NBATCH * T) return;
    int t = idx % T;
    int nb = idx / T;
    int b = nb % NBATCH;
    int n = nb / NBATCH;
    xt[idx] = X[((size_t)b * NN + n) * T + t];
}

// ---------------- launcher ----------------

static inline size_t align256(size_t x) { return (x + 255) & ~(size_t)255; }

extern "C" void kernel_launch(void* const* d_in, const int* in_sizes, int n_in,
                              void* d_out, int out_size, void* d_ws, size_t ws_size,
                              hipStream_t stream) {
    const float* Xh = (const float*)d_in[0];
    const float* Xd = (const float*)d_in[1];
    const float* Xw = (const float*)d_in[2];
    const float* A  = (const float*)d_in[3];
    const float* WD = (const float*)d_in[28];
    const float* bD = (const float*)d_in[29];

    // workspace carve
    char* p = (char*)d_ws;
    float* dinv   = (float*)p; p += align256(NN * 4);
    int* row_ptr  = (int*)p;   p += align256((NN + 1) * 4);
    int* rowcnt   = (int*)p;   p += align256(NN * 4);
    int* col_idx  = (int*)p;   p += align256((size_t)CAP * 4);
    float* val    = (float*)p; p += align256((size_t)CAP * 4);
    float* b_in   = (float*)p; p += align256((size_t)NN * NBATCH * 64 * 4);
    float* b_t1   = (float*)p; p += align256((size_t)NN * NBATCH * 64 * 4);
    float* b_t2   = (float*)p; p += align256((size_t)NN * NBATCH * 64 * 4);
    float* b_z1   = (float*)p; p += align256((size_t)NN * NBATCH * 64 * 4);
    float* b_z2   = (float*)p; p += align256((size_t)NN * NBATCH * 32 * 4);
    float* yacc   = (float*)p; p += align256((size_t)NN * NBATCH * TP * 4);

    deg_kernel<<<NN, 256, 0, stream>>>(A, dinv, rowcnt);
    scan_kernel<<<1, 1024, 0, stream>>>(rowcnt, row_ptr);
    fill_kernel<<<NN, 64, 0, stream>>>(A, dinv, row_ptr, col_idx, val);

    struct BranchP {
        const float *X; int T;
        const float *W1, *b1, *c1w, *c1b, *W2, *b2, *c2w, *c2b, *F;
    };
    BranchP br[3] = {
        { Xh, 24, (const float*)d_in[4],  (const float*)d_in[5],  (const float*)d_in[6],
                  (const float*)d_in[7],  (const float*)d_in[8],  (const float*)d_in[9],
                  (const float*)d_in[10], (const float*)d_in[11], (const float*)d_in[30] },
        { Xd, 12, (const float*)d_in[12], (const float*)d_in[13], (const float*)d_in[14],
                  (const float*)d_in[15], (const float*)d_in[16], (const float*)d_in[17],
                  (const float*)d_in[18], (const float*)d_in[19], (const float*)d_in[31] },
        { Xw, 24, (const float*)d_in[20], (const float*)d_in[21], (const float*)d_in[22],
                  (const float*)d_in[23], (const float*)d_in[24], (const float*)d_in[25],
                  (const float*)d_in[26], (const float*)d_in[27], (const float*)d_in[32] }
    };

    for (int i = 0; i < 3; ++i) {
        const BranchP& bp = br[i];
        int T = bp.T;
        int nelem = NN * NBATCH * T;
        tr_kernel<<<(nelem + 255) / 256, 256, 0, stream>>>(bp.X, b_in, T);

        // Block 1: Cin=T -> 64
        int F1 = NBATCH * T;
        int bd1 = (F1 <= 256) ? F1 : 256;
        dim3 g1(NN, (F1 + bd1 - 1) / bd1);
        spmm_kernel<false><<<g1, bd1, 0, stream>>>(row_ptr, col_idx, val, b_in, nullptr, b_t1, F1);
        spmm_kernel<true><<<g1, bd1, 0, stream>>>(row_ptr, col_idx, val, b_t1, b_in, b_t2, F1);
        if (T == 24) {
            combine_kernel<24, 64><<<NN * NBATCH, 64, 0, stream>>>(
                b_in, b_t1, b_t2, bp.W1, bp.b1, bp.c1w, bp.c1b, b_z1);
        } else {
            combine_kernel<12, 64><<<NN * NBATCH, 64, 0, stream>>>(
                b_in, b_t1, b_t2, bp.W1, bp.b1, bp.c1w, bp.c1b, b_z1);
        }

        // Block 2: 64 -> 32
        int F2 = NBATCH * 64;  // 512
        dim3 g2(NN, 2);
        spmm_kernel<false><<<g2, 256, 0, stream>>>(row_ptr, col_idx, val, b_z1, nullptr, b_t1, F2);
        spmm_kernel<true><<<g2, 256, 0, stream>>>(row_ptr, col_idx, val, b_t1, b_z1, b_t2, F2);
        combine_kernel<64, 32><<<NN * NBATCH, 32, 0, stream>>>(
            b_z1, b_t1, b_t2, bp.W2, bp.b2, bp.c2w, bp.c2b, b_z2);

        int ntot = NN * NBATCH * TP;
        finald_kernel<<<(ntot + 255) / 256, 256, 0, stream>>>(b_z2, WD, bD, bp.F, yacc, i > 0);
    }

    int ntot = NN * NBATCH * TP;
    out_kernel<<<(ntot + 255) / 256, 256, 0, stream>>>(yacc, (float*)d_out);
}

// Round 4
// 307.115 us; speedup vs baseline: 2.2998x; 1.2525x over previous
//
#include <hip/hip_runtime.h>

#define NN 3000
#define NB 8
#define TP 12
#define DMAX 128
#define F1T 480    // block-1 packed features: h(8*24) + d(8*12) + w(8*24)
#define F2T 768    // block-2 packed features: 3 * 8 * 32
#define Z1T 1536   // z1 packed: 3 * 8 * 64

struct BrW {
    const float *W1[3]; const float *b1[3]; const float *c1w[3]; const float *c1b[3];
    const float *W2[3]; const float *b2[3]; const float *c2w[3]; const float *c2b[3];
    const float *Fb[3];
};

// ---------------- one-pass Laplacian build: degree + ballot-compact ----------------
// one wave per row; writes raw A values (scaled later), padded layout [n*DMAX+j]
__global__ void build_kernel(const float* __restrict__ A, int* __restrict__ colp,
                             float* __restrict__ valp, int* __restrict__ cnt,
                             float* __restrict__ dinv) {
    int n = blockIdx.x;
    int lane = threadIdx.x;
    const float* row = A + (size_t)n * NN;
    int base = 0;
    float s = 0.f;
    for (int start = 0; start < NN; start += 64) {
        int m = start + lane;
        float a = 0.f; bool nz = false;
        if (m < NN && m != n) {
            a = row[m];
            nz = (a != 0.f);
        }
        s += a;
        unsigned long long mask = __ballot(nz);
        int off = __popcll(mask & ((1ull << lane) - 1ull));
        if (nz) {
            int idx = base + off;
            if (idx < DMAX) { colp[n * DMAX + idx] = m; valp[n * DMAX + idx] = a; }
        }
        base += __popcll(mask);
    }
    for (int o = 32; o > 0; o >>= 1) s += __shfl_down(s, o);
    if (lane == 0) {
        cnt[n] = (base < DMAX) ? base : DMAX;
        dinv[n] = (s > 0.f) ? 1.0f / sqrtf(s) : 0.f;
    }
}

__global__ void scale_kernel(const int* __restrict__ colp, float* __restrict__ valp,
                             const int* __restrict__ cnt, const float* __restrict__ dinv) {
    int n = blockIdx.x;
    int j = threadIdx.x;
    if (j < cnt[n]) {
        int m = colp[n * DMAX + j];
        valp[n * DMAX + j] *= -dinv[n] * dinv[m];
    }
}

// ---------------- pack Xh|Xd|Xw (B,N,1,T) -> xcat (N, 480) ----------------
__global__ void pack_kernel(const float* __restrict__ Xh, const float* __restrict__ Xd,
                            const float* __restrict__ Xw, float* __restrict__ xcat) {
    int idx = blockIdx.x * blockDim.x + threadIdx.x;
    if (idx >= NN * F1T) return;
    int n = idx / F1T, r = idx % F1T;
    const float* src; int b, t, T;
    if (r < 192)      { src = Xh; T = 24; int rr = r;       b = rr / 24; t = rr % 24; }
    else if (r < 288) { src = Xd; T = 12; int rr = r - 192; b = rr / 12; t = rr % 12; }
    else              { src = Xw; T = 24; int rr = r - 288; b = rr / 24; t = rr % 24; }
    xcat[idx] = src[((size_t)b * NN + n) * T + t];
}

// ---------------- SpMM with LDS-staged row + 8-deep ILP ----------------
// EPI 0: y = Lx ; EPI 1: y = 2*Lx - aux ; EPI 2: y = aux + 2*Lx
template <int F, int EPI>
__global__ void spmm_kernel(const int* __restrict__ colp, const float* __restrict__ valp,
                            const int* __restrict__ cnt, const float* __restrict__ x,
                            const float* __restrict__ aux, float* __restrict__ y) {
    int n = blockIdx.x;
    int f = blockIdx.y * 256 + threadIdx.x;
    __shared__ int   scol[DMAX];
    __shared__ float sval[DMAX];
    int c = cnt[n];
    if (threadIdx.x < DMAX) {
        int j = threadIdx.x;
        bool ok = j < c;
        scol[j] = ok ? colp[n * DMAX + j] * F : 0;
        sval[j] = ok ? valp[n * DMAX + j] : 0.f;
    }
    __syncthreads();
    int c8 = (c + 7) & ~7;
    float a0 = 0.f, a1 = 0.f, a2 = 0.f, a3 = 0.f;
    if (f < F) {
        for (int i = 0; i < c8; i += 8) {
            int   c0 = scol[i + 0], c1 = scol[i + 1], c2 = scol[i + 2], c3 = scol[i + 3];
            int   c4 = scol[i + 4], c5 = scol[i + 5], c6 = scol[i + 6], c7 = scol[i + 7];
            float w0 = sval[i + 0], w1 = sval[i + 1], w2 = sval[i + 2], w3 = sval[i + 3];
            float w4 = sval[i + 4], w5 = sval[i + 5], w6 = sval[i + 6], w7 = sval[i + 7];
            float g0 = x[c0 + f], g1 = x[c1 + f], g2 = x[c2 + f], g3 = x[c3 + f];
            float g4 = x[c4 + f], g5 = x[c5 + f], g6 = x[c6 + f], g7 = x[c7 + f];
            a0 += w0 * g0; a1 += w1 * g1; a2 += w2 * g2; a3 += w3 * g3;
            a0 += w4 * g4; a1 += w5 * g5; a2 += w6 * g6; a3 += w7 * g7;
        }
    }
    if (f >= F) return;
    float acc = (a0 + a1) + (a2 + a3);
    size_t o = (size_t)n * F + f;
    if (EPI == 1) acc = 2.f * acc - aux[o];
    else if (EPI == 2) acc = aux[o] + 2.f * acc;
    y[o] = acc;
}

// ---------------- block-1 combine: cheb + bias + relu + tconv + relu ----------------
// unit = one wave = (n, br, b); co = lane (64 output channels)
__global__ void combine1_kernel(const float* __restrict__ xcat, const float* __restrict__ t1cat,
                                const float* __restrict__ t2cat, float* __restrict__ z1cat,
                                BrW P) {
    int wid = threadIdx.x >> 6;
    int co = threadIdx.x & 63;
    int unit = blockIdx.x * 4 + wid;  // 0 .. 71999
    int br = unit / 24000;
    int nb = unit % 24000;
    int n = nb / NB, b = nb % NB;
    int T = (br == 1) ? 12 : 24;
    int off = (br == 0) ? 0 : (br == 1) ? 192 : 288;
    size_t rowbase = (size_t)n * F1T + off + b * T;
    const float* W = P.W1[br];
    float acc = P.b1[br][co];
    for (int k = 0; k < 3; ++k) {
        const float* xk = ((k == 0) ? xcat : (k == 1) ? t1cat : t2cat) + rowbase;
        const float* Wk = W + k * T * 64;
        for (int i = 0; i < T; ++i)
            acc += xk[i] * Wk[i * 64 + co];
    }
    float z = fmaxf(acc, 0.f);
    float left  = __shfl_up(z, 1);
    float right = __shfl_down(z, 1);
    if (co == 0) left = 0.f;
    if (co == 63) right = 0.f;
    float w0 = P.c1w[br][0], w1 = P.c1w[br][1], w2 = P.c1w[br][2], bb = P.c1b[br][0];
    float o = fmaxf(w0 * left + w1 * z + w2 * right + bb, 0.f);
    z1cat[(size_t)n * Z1T + br * 512 + b * 64 + co] = o;
}

// ---------------- y-GEMM: y1 = z1*W1, y2 = z1*W2, c0 = z1*W0 - y2 + b2 ----------------
__global__ void gemmy_kernel(const float* __restrict__ z1cat, float* __restrict__ y1cat,
                             float* __restrict__ y2cat, float* __restrict__ c0cat, BrW P) {
    int n = blockIdx.x, br = blockIdx.y;
    __shared__ float sz[NB * 64];
    const float* zrow_g = z1cat + (size_t)n * Z1T + br * 512;
    sz[threadIdx.x] = zrow_g[threadIdx.x];
    sz[threadIdx.x + 256] = zrow_g[threadIdx.x + 256];
    __syncthreads();
    int b = threadIdx.x >> 5, co = threadIdx.x & 31;
    const float* W = P.W2[br];               // (3, 64, 32)
    const float* W0 = W, *W1 = W + 2048, *W2 = W + 4096;
    const float* zr = sz + b * 64;
    float a0 = 0.f, a1 = 0.f, a2 = 0.f;
    for (int i = 0; i < 64; ++i) {
        float z = zr[i];
        a0 += z * W0[i * 32 + co];
        a1 += z * W1[i * 32 + co];
        a2 += z * W2[i * 32 + co];
    }
    size_t o = (size_t)n * F2T + br * 256 + b * 32 + co;
    y1cat[o] = a1;
    y2cat[o] = a2;
    c0cat[o] = a0 - a2 + P.b2[br][co];
}

// ---------------- block-2 combine + final linear + fusion, per node ----------------
// block = 768 threads; phase1: 24 half-wave units (br,b) x 32 channels
__global__ void combine2_final_kernel(const float* __restrict__ c0cat,
                                      const float* __restrict__ vcat,
                                      const float* __restrict__ WD, const float* __restrict__ bD,
                                      float* __restrict__ out, BrW P) {
    int n = blockIdx.x;
    __shared__ float z2[3][NB][32];
    int unit = threadIdx.x >> 5;      // 0..23
    int co = threadIdx.x & 31;
    int br = unit >> 3, b = unit & 7;
    size_t o = (size_t)n * F2T + br * 256 + b * 32 + co;
    float a = fmaxf(c0cat[o] + vcat[o], 0.f);
    float left  = __shfl_up(a, 1);
    float right = __shfl_down(a, 1);
    if (co == 0) left = 0.f;
    if (co == 31) right = 0.f;
    float w0 = P.c2w[br][0], w1 = P.c2w[br][1], w2 = P.c2w[br][2], bb = P.c2b[br][0];
    z2[br][b][co] = fmaxf(w0 * left + w1 * a + w2 * right + bb, 0.f);
    __syncthreads();
    if (threadIdx.x < NB * TP) {
        int b2 = threadIdx.x / TP, tp = threadIdx.x % TP;
        float y = 0.f;
        for (int brr = 0; brr < 3; ++brr) {
            float s = bD[tp];
            const float* zz = z2[brr][b2];
            for (int c = 0; c < 32; ++c) s += zz[c] * WD[c * TP + tp];
            y += fmaxf(s, 0.f) * P.Fb[brr][tp];
        }
        out[((size_t)b2 * NN + n) * TP + tp] = y;
    }
}

// ---------------- launcher ----------------

static inline size_t align256(size_t x) { return (x + 255) & ~(size_t)255; }

extern "C" void kernel_launch(void* const* d_in, const int* in_sizes, int n_in,
                              void* d_out, int out_size, void* d_ws, size_t ws_size,
                              hipStream_t stream) {
    const float* Xh = (const float*)d_in[0];
    const float* Xd = (const float*)d_in[1];
    const float* Xw = (const float*)d_in[2];
    const float* A  = (const float*)d_in[3];
    const float* WD = (const float*)d_in[28];
    const float* bD = (const float*)d_in[29];

    BrW P;
    for (int br = 0; br < 3; ++br) {
        int base = 4 + br * 8;
        P.W1[br]  = (const float*)d_in[base + 0];
        P.b1[br]  = (const float*)d_in[base + 1];
        P.c1w[br] = (const float*)d_in[base + 2];
        P.c1b[br] = (const float*)d_in[base + 3];
        P.W2[br]  = (const float*)d_in[base + 4];
        P.b2[br]  = (const float*)d_in[base + 5];
        P.c2w[br] = (const float*)d_in[base + 6];
        P.c2b[br] = (const float*)d_in[base + 7];
        P.Fb[br]  = (const float*)d_in[30 + br];
    }

    char* p = (char*)d_ws;
    int*   colp  = (int*)p;   p += align256((size_t)NN * DMAX * 4);
    float* valp  = (float*)p; p += align256((size_t)NN * DMAX * 4);
    int*   cnt   = (int*)p;   p += align256(NN * 4);
    float* dinv  = (float*)p; p += align256(NN * 4);
    float* xcat  = (float*)p; p += align256((size_t)NN * F1T * 4);
    float* t1cat = (float*)p; p += align256((size_t)NN * F1T * 4);
    float* t2cat = (float*)p; p += align256((size_t)NN * F1T * 4);
    float* z1cat = (float*)p; p += align256((size_t)NN * Z1T * 4);
    float* y1cat = (float*)p; p += align256((size_t)NN * F2T * 4);
    float* y2cat = (float*)p; p += align256((size_t)NN * F2T * 4);
    float* c0cat = (float*)p; p += align256((size_t)NN * F2T * 4);
    float* scat  = (float*)p; p += align256((size_t)NN * F2T * 4);
    float* vcat  = (float*)p; p += align256((size_t)NN * F2T * 4);

    build_kernel<<<NN, 64, 0, stream>>>(A, colp, valp, cnt, dinv);
    scale_kernel<<<NN, DMAX, 0, stream>>>(colp, valp, cnt, dinv);
    pack_kernel<<<(NN * F1T + 255) / 256, 256, 0, stream>>>(Xh, Xd, Xw, xcat);

    // Block 1 (all branches packed, F=480): t1 = L x ; t2 = 2 L t1 - x
    spmm_kernel<F1T, 0><<<dim3(NN, 2), 256, 0, stream>>>(colp, valp, cnt, xcat, nullptr, t1cat);
    spmm_kernel<F1T, 1><<<dim3(NN, 2), 256, 0, stream>>>(colp, valp, cnt, t1cat, xcat, t2cat);
    combine1_kernel<<<18000, 256, 0, stream>>>(xcat, t1cat, t2cat, z1cat, P);

    // Block 2 W-first: y1,y2,c0 ; s = y1 + 2 L y2 ; v = L s ; out2 = relu(c0 + v)...
    gemmy_kernel<<<dim3(NN, 3), 256, 0, stream>>>(z1cat, y1cat, y2cat, c0cat, P);
    spmm_kernel<F2T, 2><<<dim3(NN, 3), 256, 0, stream>>>(colp, valp, cnt, y2cat, y1cat, scat);
    spmm_kernel<F2T, 0><<<dim3(NN, 3), 256, 0, stream>>>(colp, valp, cnt, scat, nullptr, vcat);

    combine2_final_kernel<<<NN, 768, 0, stream>>>(c0cat, vcat, WD, bD, (float*)d_out, P);
}

// Round 5
// 246.765 us; speedup vs baseline: 2.8622x; 1.2446x over previous
//
#include <hip/hip_runtime.h>

#define NN 3000
#define NB 8
#define TP 12
#define DMAX 128
#define F1T 480    // block-1 packed features: h(8*24) + d(8*12) + w(8*24)
#define F2T 768    // block-2 packed features: 3 * 8 * 32
#define Z1T 1536   // z1 packed: 3 * 8 * 64

struct BrW {
    const float *W1[3]; const float *b1[3]; const float *c1w[3]; const float *c1b[3];
    const float *W2[3]; const float *b2[3]; const float *c2w[3]; const float *c2b[3];
    const float *Fb[3];
};

// ---------------- one-pass Laplacian build: degree + ballot-compact ----------------
__global__ void build_kernel(const float* __restrict__ A, int* __restrict__ colp,
                             float* __restrict__ valp, int* __restrict__ cnt,
                             float* __restrict__ dinv) {
    int n = blockIdx.x;
    int lane = threadIdx.x;
    const float* row = A + (size_t)n * NN;
    int base = 0;
    float s = 0.f;
    for (int start = 0; start < NN; start += 64) {
        int m = start + lane;
        float a = 0.f; bool nz = false;
        if (m < NN && m != n) {
            a = row[m];
            nz = (a != 0.f);
        }
        s += a;
        unsigned long long mask = __ballot(nz);
        int off = __popcll(mask & ((1ull << lane) - 1ull));
        if (nz) {
            int idx = base + off;
            if (idx < DMAX) { colp[n * DMAX + idx] = m; valp[n * DMAX + idx] = a; }
        }
        base += __popcll(mask);
    }
    for (int o = 32; o > 0; o >>= 1) s += __shfl_down(s, o);
    if (lane == 0) {
        cnt[n] = (base < DMAX) ? base : DMAX;
        dinv[n] = (s > 0.f) ? 1.0f / sqrtf(s) : 0.f;
    }
}

__global__ void scale_kernel(const int* __restrict__ colp, float* __restrict__ valp,
                             const int* __restrict__ cnt, const float* __restrict__ dinv) {
    int n = blockIdx.x;
    int j = threadIdx.x;
    if (j < cnt[n]) {
        int m = colp[n * DMAX + j];
        valp[n * DMAX + j] *= -dinv[n] * dinv[m];
    }
}

// ---------------- pack Xh|Xd|Xw (B,N,1,T) -> xcat (N, 480) ----------------
__global__ void pack_kernel(const float* __restrict__ Xh, const float* __restrict__ Xd,
                            const float* __restrict__ Xw, float* __restrict__ xcat) {
    int idx = blockIdx.x * blockDim.x + threadIdx.x;
    if (idx >= NN * F1T) return;
    int n = idx / F1T, r = idx % F1T;
    const float* src; int b, t, T;
    if (r < 192)      { src = Xh; T = 24; int rr = r;       b = rr / 24; t = rr % 24; }
    else if (r < 288) { src = Xd; T = 12; int rr = r - 192; b = rr / 12; t = rr % 12; }
    else              { src = Xw; T = 24; int rr = r - 288; b = rr / 24; t = rr % 24; }
    xcat[idx] = src[((size_t)b * NN + n) * T + t];
}

// ---------------- SpMM with LDS-staged row + 8-deep ILP ----------------
// EPI 0: y = Lx ; EPI 1: y = 2*Lx - aux ; EPI 2: y = aux + 2*Lx
template <int F, int EPI>
__global__ void spmm_kernel(const int* __restrict__ colp, const float* __restrict__ valp,
                            const int* __restrict__ cnt, const float* __restrict__ x,
                            const float* __restrict__ aux, float* __restrict__ y) {
    int n = blockIdx.x;
    int f = blockIdx.y * 256 + threadIdx.x;
    __shared__ int   scol[DMAX];
    __shared__ float sval[DMAX];
    int c = cnt[n];
    if (threadIdx.x < DMAX) {
        int j = threadIdx.x;
        bool ok = j < c;
        scol[j] = ok ? colp[n * DMAX + j] * F : 0;
        sval[j] = ok ? valp[n * DMAX + j] : 0.f;
    }
    __syncthreads();
    int c8 = (c + 7) & ~7;
    float a0 = 0.f, a1 = 0.f, a2 = 0.f, a3 = 0.f;
    if (f < F) {
        for (int i = 0; i < c8; i += 8) {
            int   c0 = scol[i + 0], c1 = scol[i + 1], c2 = scol[i + 2], c3 = scol[i + 3];
            int   c4 = scol[i + 4], c5 = scol[i + 5], c6 = scol[i + 6], c7 = scol[i + 7];
            float w0 = sval[i + 0], w1 = sval[i + 1], w2 = sval[i + 2], w3 = sval[i + 3];
            float w4 = sval[i + 4], w5 = sval[i + 5], w6 = sval[i + 6], w7 = sval[i + 7];
            float g0 = x[c0 + f], g1 = x[c1 + f], g2 = x[c2 + f], g3 = x[c3 + f];
            float g4 = x[c4 + f], g5 = x[c5 + f], g6 = x[c6 + f], g7 = x[c7 + f];
            a0 += w0 * g0; a1 += w1 * g1; a2 += w2 * g2; a3 += w3 * g3;
            a0 += w4 * g4; a1 += w5 * g5; a2 += w6 * g6; a3 += w7 * g7;
        }
    }
    if (f >= F) return;
    float acc = (a0 + a1) + (a2 + a3);
    size_t o = (size_t)n * F + f;
    if (EPI == 1) acc = 2.f * acc - aux[o];
    else if (EPI == 2) acc = aux[o] + 2.f * acc;
    y[o] = acc;
}

// ---------------- block-1 combine: cheb + bias + relu + tconv + relu ----------------
// Templated per-branch: compile-time T -> full unroll; x broadcast via shfl.
// unit = one wave = (n, b); co = lane (64 output channels)
template <int T, int OFF, int BROFF>
__global__ void combine1_kernel(const float* __restrict__ xcat, const float* __restrict__ t1cat,
                                const float* __restrict__ t2cat, float* __restrict__ z1cat,
                                const float* __restrict__ W, const float* __restrict__ bg,
                                const float* __restrict__ cw, const float* __restrict__ cb) {
    int wid = threadIdx.x >> 6;
    int co = threadIdx.x & 63;
    int unit = blockIdx.x * 4 + wid;  // 0 .. 23999
    int n = unit / NB, b = unit % NB;
    size_t rowbase = (size_t)n * F1T + OFF + b * T;
    float xv0 = 0.f, xv1 = 0.f, xv2 = 0.f;
    if (co < T) {
        xv0 = xcat[rowbase + co];
        xv1 = t1cat[rowbase + co];
        xv2 = t2cat[rowbase + co];
    }
    float acc = bg[co];
    #pragma unroll
    for (int i = 0; i < T; ++i)
        acc += __shfl(xv0, i) * W[i * 64 + co];
    #pragma unroll
    for (int i = 0; i < T; ++i)
        acc += __shfl(xv1, i) * W[(T + i) * 64 + co];
    #pragma unroll
    for (int i = 0; i < T; ++i)
        acc += __shfl(xv2, i) * W[(2 * T + i) * 64 + co];
    float z = fmaxf(acc, 0.f);
    float left  = __shfl_up(z, 1);
    float right = __shfl_down(z, 1);
    if (co == 0) left = 0.f;
    if (co == 63) right = 0.f;
    float w0 = cw[0], w1 = cw[1], w2 = cw[2], bb = cb[0];
    float o = fmaxf(w0 * left + w1 * z + w2 * right + bb, 0.f);
    z1cat[(size_t)n * Z1T + BROFF + b * 64 + co] = o;
}

// ---------------- y-GEMM: y1 = z1*W1, y2 = z1*W2, c0 = z1*W0 - y2 + b2 ----------------
__global__ void gemmy_kernel(const float* __restrict__ z1cat, float* __restrict__ y1cat,
                             float* __restrict__ y2cat, float* __restrict__ c0cat, BrW P) {
    int n = blockIdx.x, br = blockIdx.y;
    __shared__ float sz[NB * 64];
    const float* zrow_g = z1cat + (size_t)n * Z1T + br * 512;
    sz[threadIdx.x] = zrow_g[threadIdx.x];
    sz[threadIdx.x + 256] = zrow_g[threadIdx.x + 256];
    __syncthreads();
    int b = threadIdx.x >> 5, co = threadIdx.x & 31;
    const float* W = P.W2[br];               // (3, 64, 32)
    const float* W0 = W, *W1 = W + 2048, *W2 = W + 4096;
    const float* zr = sz + b * 64;
    float a0 = 0.f, a1 = 0.f, a2 = 0.f;
    for (int i = 0; i < 64; ++i) {
        float z = zr[i];
        a0 += z * W0[i * 32 + co];
        a1 += z * W1[i * 32 + co];
        a2 += z * W2[i * 32 + co];
    }
    size_t o = (size_t)n * F2T + br * 256 + b * 32 + co;
    y1cat[o] = a1;
    y2cat[o] = a2;
    c0cat[o] = a0 - a2 + P.b2[br][co];
}

// ---------------- block-2 combine + final linear + fusion, per node ----------------
__global__ void combine2_final_kernel(const float* __restrict__ c0cat,
                                      const float* __restrict__ vcat,
                                      const float* __restrict__ WD, const float* __restrict__ bD,
                                      float* __restrict__ out, BrW P) {
    int n = blockIdx.x;
    __shared__ float z2[3][NB][32];
    int unit = threadIdx.x >> 5;      // 0..23
    int co = threadIdx.x & 31;
    int br = unit >> 3, b = unit & 7;
    size_t o = (size_t)n * F2T + br * 256 + b * 32 + co;
    float a = fmaxf(c0cat[o] + vcat[o], 0.f);
    float left  = __shfl_up(a, 1);
    float right = __shfl_down(a, 1);
    if (co == 0) left = 0.f;
    if (co == 31) right = 0.f;
    float w0 = P.c2w[br][0], w1 = P.c2w[br][1], w2 = P.c2w[br][2], bb = P.c2b[br][0];
    z2[br][b][co] = fmaxf(w0 * left + w1 * a + w2 * right + bb, 0.f);
    __syncthreads();
    if (threadIdx.x < NB * TP) {
        int b2 = threadIdx.x / TP, tp = threadIdx.x % TP;
        float y = 0.f;
        for (int brr = 0; brr < 3; ++brr) {
            float s = bD[tp];
            const float* zz = z2[brr][b2];
            for (int c = 0; c < 32; ++c) s += zz[c] * WD[c * TP + tp];
            y += fmaxf(s, 0.f) * P.Fb[brr][tp];
        }
        out[((size_t)b2 * NN + n) * TP + tp] = y;
    }
}

// ---------------- launcher ----------------

static inline size_t align256(size_t x) { return (x + 255) & ~(size_t)255; }

extern "C" void kernel_launch(void* const* d_in, const int* in_sizes, int n_in,
                              void* d_out, int out_size, void* d_ws, size_t ws_size,
                              hipStream_t stream) {
    const float* Xh = (const float*)d_in[0];
    const float* Xd = (const float*)d_in[1];
    const float* Xw = (const float*)d_in[2];
    const float* A  = (const float*)d_in[3];
    const float* WD = (const float*)d_in[28];
    const float* bD = (const float*)d_in[29];

    BrW P;
    for (int br = 0; br < 3; ++br) {
        int base = 4 + br * 8;
        P.W1[br]  = (const float*)d_in[base + 0];
        P.b1[br]  = (const float*)d_in[base + 1];
        P.c1w[br] = (const float*)d_in[base + 2];
        P.c1b[br] = (const float*)d_in[base + 3];
        P.W2[br]  = (const float*)d_in[base + 4];
        P.b2[br]  = (const float*)d_in[base + 5];
        P.c2w[br] = (const float*)d_in[base + 6];
        P.c2b[br] = (const float*)d_in[base + 7];
        P.Fb[br]  = (const float*)d_in[30 + br];
    }

    char* p = (char*)d_ws;
    int*   colp  = (int*)p;   p += align256((size_t)NN * DMAX * 4);
    float* valp  = (float*)p; p += align256((size_t)NN * DMAX * 4);
    int*   cnt   = (int*)p;   p += align256(NN * 4);
    float* dinv  = (float*)p; p += align256(NN * 4);
    float* xcat  = (float*)p; p += align256((size_t)NN * F1T * 4);
    float* t1cat = (float*)p; p += align256((size_t)NN * F1T * 4);
    float* t2cat = (float*)p; p += align256((size_t)NN * F1T * 4);
    float* z1cat = (float*)p; p += align256((size_t)NN * Z1T * 4);
    float* y1cat = (float*)p; p += align256((size_t)NN * F2T * 4);
    float* y2cat = (float*)p; p += align256((size_t)NN * F2T * 4);
    float* c0cat = (float*)p; p += align256((size_t)NN * F2T * 4);
    float* scat  = (float*)p; p += align256((size_t)NN * F2T * 4);
    float* vcat  = (float*)p; p += align256((size_t)NN * F2T * 4);

    build_kernel<<<NN, 64, 0, stream>>>(A, colp, valp, cnt, dinv);
    scale_kernel<<<NN, DMAX, 0, stream>>>(colp, valp, cnt, dinv);
    pack_kernel<<<(NN * F1T + 255) / 256, 256, 0, stream>>>(Xh, Xd, Xw, xcat);

    // Block 1 (all branches packed, F=480): t1 = L x ; t2 = 2 L t1 - x
    spmm_kernel<F1T, 0><<<dim3(NN, 2), 256, 0, stream>>>(colp, valp, cnt, xcat, nullptr, t1cat);
    spmm_kernel<F1T, 1><<<dim3(NN, 2), 256, 0, stream>>>(colp, valp, cnt, t1cat, xcat, t2cat);
    combine1_kernel<24, 0, 0><<<6000, 256, 0, stream>>>(
        xcat, t1cat, t2cat, z1cat, P.W1[0], P.b1[0], P.c1w[0], P.c1b[0]);
    combine1_kernel<12, 192, 512><<<6000, 256, 0, stream>>>(
        xcat, t1cat, t2cat, z1cat, P.W1[1], P.b1[1], P.c1w[1], P.c1b[1]);
    combine1_kernel<24, 288, 1024><<<6000, 256, 0, stream>>>(
        xcat, t1cat, t2cat, z1cat, P.W1[2], P.b1[2], P.c1w[2], P.c1b[2]);

    // Block 2 W-first: y1,y2,c0 ; s = y1 + 2 L y2 ; v = L s ; out2 = relu(c0 + v)...
    gemmy_kernel<<<dim3(NN, 3), 256, 0, stream>>>(z1cat, y1cat, y2cat, c0cat, P);
    spmm_kernel<F2T, 2><<<dim3(NN, 3), 256, 0, stream>>>(colp, valp, cnt, y2cat, y1cat, scat);
    spmm_kernel<F2T, 0><<<dim3(NN, 3), 256, 0, stream>>>(colp, valp, cnt, scat, nullptr, vcat);

    combine2_final_kernel<<<NN, 768, 0, stream>>>(c0cat, vcat, WD, bD, (float*)d_out, P);
}

// Round 6
// 229.101 us; speedup vs baseline: 3.0829x; 1.0771x over previous
//
#include <hip/hip_runtime.h>

#define NN 3000
#define NB 8
#define TP 12
#define DMAX 128
#define F1T 480    // block-1 packed features: h(8*24) + d(8*12) + w(8*24)
#define F2T 768    // block-2 packed features: 3 * 8 * 32
#define Z1T 1536   // z1 packed: 3 * 8 * 64

struct BrW {
    const float *W1[3]; const float *b1[3]; const float *c1w[3]; const float *c1b[3];
    const float *W2[3]; const float *b2[3]; const float *c2w[3]; const float *c2b[3];
    const float *Fb[3];
};

// ---------------- one-pass Laplacian build: degree + ballot-compact ----------------
__global__ void build_kernel(const float* __restrict__ A, int* __restrict__ colp,
                             float* __restrict__ valp, int* __restrict__ cnt,
                             float* __restrict__ dinv) {
    int n = blockIdx.x;
    int lane = threadIdx.x;
    const float* row = A + (size_t)n * NN;
    int base = 0;
    float s = 0.f;
    for (int start = 0; start < NN; start += 64) {
        int m = start + lane;
        float a = 0.f; bool nz = false;
        if (m < NN && m != n) {
            a = row[m];
            nz = (a != 0.f);
        }
        s += a;
        unsigned long long mask = __ballot(nz);
        int off = __popcll(mask & ((1ull << lane) - 1ull));
        if (nz) {
            int idx = base + off;
            if (idx < DMAX) { colp[n * DMAX + idx] = m; valp[n * DMAX + idx] = a; }
        }
        base += __popcll(mask);
    }
    for (int o = 32; o > 0; o >>= 1) s += __shfl_down(s, o);
    if (lane == 0) {
        cnt[n] = (base < DMAX) ? base : DMAX;
        dinv[n] = (s > 0.f) ? 1.0f / sqrtf(s) : 0.f;
    }
}

__global__ void scale_kernel(const int* __restrict__ colp, float* __restrict__ valp,
                             const int* __restrict__ cnt, const float* __restrict__ dinv) {
    int n = blockIdx.x;
    int j = threadIdx.x;
    if (j < cnt[n]) {
        int m = colp[n * DMAX + j];
        valp[n * DMAX + j] *= -dinv[n] * dinv[m];
    }
}

// ---------------- pack Xh|Xd|Xw (B,N,1,T) -> xcat (N, 480) ----------------
__global__ void pack_kernel(const float* __restrict__ Xh, const float* __restrict__ Xd,
                            const float* __restrict__ Xw, float* __restrict__ xcat) {
    int idx = blockIdx.x * blockDim.x + threadIdx.x;
    if (idx >= NN * F1T) return;
    int n = idx / F1T, r = idx % F1T;
    const float* src; int b, t, T;
    if (r < 192)      { src = Xh; T = 24; int rr = r;       b = rr / 24; t = rr % 24; }
    else if (r < 288) { src = Xd; T = 12; int rr = r - 192; b = rr / 12; t = rr % 12; }
    else              { src = Xw; T = 24; int rr = r - 288; b = rr / 24; t = rr % 24; }
    xcat[idx] = src[((size_t)b * NN + n) * T + t];
}

// ---------------- SpMM with LDS-staged row + 8-deep ILP ----------------
// EPI 0: y = Lx ; EPI 1: y = 2*Lx - aux ; EPI 2: y = aux + 2*Lx
template <int F, int EPI>
__global__ void spmm_kernel(const int* __restrict__ colp, const float* __restrict__ valp,
                            const int* __restrict__ cnt, const float* __restrict__ x,
                            const float* __restrict__ aux, float* __restrict__ y) {
    int n = blockIdx.x;
    int f = blockIdx.y * 256 + threadIdx.x;
    __shared__ int   scol[DMAX];
    __shared__ float sval[DMAX];
    int c = cnt[n];
    if (threadIdx.x < DMAX) {
        int j = threadIdx.x;
        bool ok = j < c;
        scol[j] = ok ? colp[n * DMAX + j] * F : 0;
        sval[j] = ok ? valp[n * DMAX + j] : 0.f;
    }
    __syncthreads();
    int c8 = (c + 7) & ~7;
    float a0 = 0.f, a1 = 0.f, a2 = 0.f, a3 = 0.f;
    if (f < F) {
        for (int i = 0; i < c8; i += 8) {
            int   c0 = scol[i + 0], c1 = scol[i + 1], c2 = scol[i + 2], c3 = scol[i + 3];
            int   c4 = scol[i + 4], c5 = scol[i + 5], c6 = scol[i + 6], c7 = scol[i + 7];
            float w0 = sval[i + 0], w1 = sval[i + 1], w2 = sval[i + 2], w3 = sval[i + 3];
            float w4 = sval[i + 4], w5 = sval[i + 5], w6 = sval[i + 6], w7 = sval[i + 7];
            float g0 = x[c0 + f], g1 = x[c1 + f], g2 = x[c2 + f], g3 = x[c3 + f];
            float g4 = x[c4 + f], g5 = x[c5 + f], g6 = x[c6 + f], g7 = x[c7 + f];
            a0 += w0 * g0; a1 += w1 * g1; a2 += w2 * g2; a3 += w3 * g3;
            a0 += w4 * g4; a1 += w5 * g5; a2 += w6 * g6; a3 += w7 * g7;
        }
    }
    if (f >= F) return;
    float acc = (a0 + a1) + (a2 + a3);
    size_t o = (size_t)n * F + f;
    if (EPI == 1) acc = 2.f * acc - aux[o];
    else if (EPI == 2) acc = aux[o] + 2.f * acc;
    y[o] = acc;
}

// ---------------- block-1 combine: cheb + bias + relu + tconv + relu ----------------
template <int T, int OFF, int BROFF>
__global__ void combine1_kernel(const float* __restrict__ xcat, const float* __restrict__ t1cat,
                                const float* __restrict__ t2cat, float* __restrict__ z1cat,
                                const float* __restrict__ W, const float* __restrict__ bg,
                                const float* __restrict__ cw, const float* __restrict__ cb) {
    int wid = threadIdx.x >> 6;
    int co = threadIdx.x & 63;
    int unit = blockIdx.x * 4 + wid;  // 0 .. 23999
    int n = unit / NB, b = unit % NB;
    size_t rowbase = (size_t)n * F1T + OFF + b * T;
    float xv0 = 0.f, xv1 = 0.f, xv2 = 0.f;
    if (co < T) {
        xv0 = xcat[rowbase + co];
        xv1 = t1cat[rowbase + co];
        xv2 = t2cat[rowbase + co];
    }
    float acc = bg[co];
    #pragma unroll
    for (int i = 0; i < T; ++i)
        acc += __shfl(xv0, i) * W[i * 64 + co];
    #pragma unroll
    for (int i = 0; i < T; ++i)
        acc += __shfl(xv1, i) * W[(T + i) * 64 + co];
    #pragma unroll
    for (int i = 0; i < T; ++i)
        acc += __shfl(xv2, i) * W[(2 * T + i) * 64 + co];
    float z = fmaxf(acc, 0.f);
    float left  = __shfl_up(z, 1);
    float right = __shfl_down(z, 1);
    if (co == 0) left = 0.f;
    if (co == 63) right = 0.f;
    float w0 = cw[0], w1 = cw[1], w2 = cw[2], bb = cb[0];
    float o = fmaxf(w0 * left + w1 * z + w2 * right + bb, 0.f);
    z1cat[(size_t)n * Z1T + BROFF + b * 64 + co] = o;
}

// ---------------- tiled y-GEMM: 32 rows x 96 cols per block, K=64 ----------------
// sW layout interleaved c = j*3 + m so each thread's 12 cols = 4 complete (a0,a1,a2) triples.
#define GROWS 32
__global__ void gemmy_kernel(const float* __restrict__ z1cat, float* __restrict__ y1cat,
                             float* __restrict__ y2cat, float* __restrict__ c0cat, BrW P) {
    int tile = blockIdx.x;   // 0..749 (24000 rows / 32)
    int br = blockIdx.y;
    __shared__ float sW[64 * 96];        // 24 KB; sW[k*96 + j*3 + m] = W[m][k][j]
    __shared__ float sZ[GROWS * 65];     // padded: bank-conflict-free broadcast
    const float* W = P.W2[br];           // (3, 64, 32)
    for (int i = threadIdx.x; i < 6144; i += 256) {
        int k = i / 96, c = i % 96;
        int j = c / 3, m = c % 3;
        sW[i] = W[m * 2048 + k * 32 + j];
    }
    int row0 = tile * GROWS;
    for (int i = threadIdx.x; i < GROWS * 64; i += 256) {
        int r = i >> 6, k = i & 63;
        int rg = row0 + r;
        int n = rg >> 3, b = rg & 7;
        sZ[r * 65 + k] = z1cat[(size_t)n * Z1T + br * 512 + b * 64 + k];
    }
    __syncthreads();

    int r = threadIdx.x >> 3;        // 0..31
    int g = threadIdx.x & 7;         // 0..7 -> cols g*12 .. g*12+11
    float acc[12];
    #pragma unroll
    for (int j = 0; j < 12; ++j) acc[j] = 0.f;
    const float* zrow = sZ + r * 65;
    #pragma unroll 4
    for (int k = 0; k < 64; ++k) {
        float zv = zrow[k];
        const float4* wr = reinterpret_cast<const float4*>(sW + k * 96 + g * 12);
        float4 wa = wr[0], wb = wr[1], wc = wr[2];
        acc[0] += zv * wa.x; acc[1] += zv * wa.y; acc[2]  += zv * wa.z; acc[3]  += zv * wa.w;
        acc[4] += zv * wb.x; acc[5] += zv * wb.y; acc[6]  += zv * wb.z; acc[7]  += zv * wb.w;
        acc[8] += zv * wc.x; acc[9] += zv * wc.y; acc[10] += zv * wc.z; acc[11] += zv * wc.w;
    }

    int rg = row0 + r;
    int n = rg >> 3, b = rg & 7;
    size_t obase = (size_t)n * F2T + br * 256 + b * 32;
    const float* b2 = P.b2[br];
    #pragma unroll
    for (int jj = 0; jj < 4; ++jj) {
        int j = g * 4 + jj;          // output column 0..31
        float a0 = acc[jj * 3 + 0], a1 = acc[jj * 3 + 1], a2 = acc[jj * 3 + 2];
        y1cat[obase + j] = a1;
        y2cat[obase + j] = a2;
        c0cat[obase + j] = a0 - a2 + b2[j];
    }
}

// ---------------- block-2 combine + final linear + fusion, per node ----------------
__global__ void combine2_final_kernel(const float* __restrict__ c0cat,
                                      const float* __restrict__ vcat,
                                      const float* __restrict__ WD, const float* __restrict__ bD,
                                      float* __restrict__ out, BrW P) {
    int n = blockIdx.x;
    __shared__ float z2[3][NB][32];
    int unit = threadIdx.x >> 5;      // 0..23
    int co = threadIdx.x & 31;
    int br = unit >> 3, b = unit & 7;
    size_t o = (size_t)n * F2T + br * 256 + b * 32 + co;
    float a = fmaxf(c0cat[o] + vcat[o], 0.f);
    float left  = __shfl_up(a, 1);
    float right = __shfl_down(a, 1);
    if (co == 0) left = 0.f;
    if (co == 31) right = 0.f;
    float w0 = P.c2w[br][0], w1 = P.c2w[br][1], w2 = P.c2w[br][2], bb = P.c2b[br][0];
    z2[br][b][co] = fmaxf(w0 * left + w1 * a + w2 * right + bb, 0.f);
    __syncthreads();
    if (threadIdx.x < NB * TP) {
        int b2 = threadIdx.x / TP, tp = threadIdx.x % TP;
        float y = 0.f;
        for (int brr = 0; brr < 3; ++brr) {
            float s = bD[tp];
            const float* zz = z2[brr][b2];
            for (int c = 0; c < 32; ++c) s += zz[c] * WD[c * TP + tp];
            y += fmaxf(s, 0.f) * P.Fb[brr][tp];
        }
        out[((size_t)b2 * NN + n) * TP + tp] = y;
    }
}

// ---------------- launcher ----------------

static inline size_t align256(size_t x) { return (x + 255) & ~(size_t)255; }

extern "C" void kernel_launch(void* const* d_in, const int* in_sizes, int n_in,
                              void* d_out, int out_size, void* d_ws, size_t ws_size,
                              hipStream_t stream) {
    const float* Xh = (const float*)d_in[0];
    const float* Xd = (const float*)d_in[1];
    const float* Xw = (const float*)d_in[2];
    const float* A  = (const float*)d_in[3];
    const float* WD = (const float*)d_in[28];
    const float* bD = (const float*)d_in[29];

    BrW P;
    for (int br = 0; br < 3; ++br) {
        int base = 4 + br * 8;
        P.W1[br]  = (const float*)d_in[base + 0];
        P.b1[br]  = (const float*)d_in[base + 1];
        P.c1w[br] = (const float*)d_in[base + 2];
        P.c1b[br] = (const float*)d_in[base + 3];
        P.W2[br]  = (const float*)d_in[base + 4];
        P.b2[br]  = (const float*)d_in[base + 5];
        P.c2w[br] = (const float*)d_in[base + 6];
        P.c2b[br] = (const float*)d_in[base + 7];
        P.Fb[br]  = (const float*)d_in[30 + br];
    }

    char* p = (char*)d_ws;
    int*   colp  = (int*)p;   p += align256((size_t)NN * DMAX * 4);
    float* valp  = (float*)p; p += align256((size_t)NN * DMAX * 4);
    int*   cnt   = (int*)p;   p += align256(NN * 4);
    float* dinv  = (float*)p; p += align256(NN * 4);
    float* xcat  = (float*)p; p += align256((size_t)NN * F1T * 4);
    float* t1cat = (float*)p; p += align256((size_t)NN * F1T * 4);
    float* t2cat = (float*)p; p += align256((size_t)NN * F1T * 4);
    float* z1cat = (float*)p; p += align256((size_t)NN * Z1T * 4);
    float* y1cat = (float*)p; p += align256((size_t)NN * F2T * 4);
    float* y2cat = (float*)p; p += align256((size_t)NN * F2T * 4);
    float* c0cat = (float*)p; p += align256((size_t)NN * F2T * 4);
    float* scat  = (float*)p; p += align256((size_t)NN * F2T * 4);
    float* vcat  = (float*)p; p += align256((size_t)NN * F2T * 4);

    build_kernel<<<NN, 64, 0, stream>>>(A, colp, valp, cnt, dinv);
    scale_kernel<<<NN, DMAX, 0, stream>>>(colp, valp, cnt, dinv);
    pack_kernel<<<(NN * F1T + 255) / 256, 256, 0, stream>>>(Xh, Xd, Xw, xcat);

    // Block 1 (all branches packed, F=480): t1 = L x ; t2 = 2 L t1 - x
    spmm_kernel<F1T, 0><<<dim3(NN, 2), 256, 0, stream>>>(colp, valp, cnt, xcat, nullptr, t1cat);
    spmm_kernel<F1T, 1><<<dim3(NN, 2), 256, 0, stream>>>(colp, valp, cnt, t1cat, xcat, t2cat);
    combine1_kernel<24, 0, 0><<<6000, 256, 0, stream>>>(
        xcat, t1cat, t2cat, z1cat, P.W1[0], P.b1[0], P.c1w[0], P.c1b[0]);
    combine1_kernel<12, 192, 512><<<6000, 256, 0, stream>>>(
        xcat, t1cat, t2cat, z1cat, P.W1[1], P.b1[1], P.c1w[1], P.c1b[1]);
    combine1_kernel<24, 288, 1024><<<6000, 256, 0, stream>>>(
        xcat, t1cat, t2cat, z1cat, P.W1[2], P.b1[2], P.c1w[2], P.c1b[2]);

    // Block 2 W-first: y1,y2,c0 ; s = y1 + 2 L y2 ; v = L s ; out2 = relu(c0 + v)...
    gemmy_kernel<<<dim3(750, 3), 256, 0, stream>>>(z1cat, y1cat, y2cat, c0cat, P);
    spmm_kernel<F2T, 2><<<dim3(NN, 3), 256, 0, stream>>>(colp, valp, cnt, y2cat, y1cat, scat);
    spmm_kernel<F2T, 0><<<dim3(NN, 3), 256, 0, stream>>>(colp, valp, cnt, scat, nullptr, vcat);

    combine2_final_kernel<<<NN, 768, 0, stream>>>(c0cat, vcat, WD, bD, (float*)d_out, P);
}